// Round 2
// baseline (12457.619 us; speedup 1.0000x reference)
//
#include <hip/hip_runtime.h>

#define B_ 128
#define S_ 4096
#define IN_ 6
#define N_ 64
#define MOT_ 3
#define UNF 6
#define EPS_ 1e-8f
#define LOG2E 1.4426950408889634f

// One workgroup per batch element. 512 threads = 8 waves.
// Thread t: i = t&63 (output neuron / column), c = t>>6 (j-chunk of 8 rows).
// Synapse params live in registers; v state broadcast through LDS.
__launch_bounds__(512, 1)
__global__ void ltc_kernel(
    const float* __restrict__ x,
    const float* __restrict__ mean_us, const float* __restrict__ std_us,
    const float* __restrict__ input_w, const float* __restrict__ input_b,
    const float* __restrict__ output_w, const float* __restrict__ output_b,
    const float* __restrict__ gleak, const float* __restrict__ vleak,
    const float* __restrict__ cm,
    const float* __restrict__ sW, const float* __restrict__ sMu,
    const float* __restrict__ sSig, const float* __restrict__ sErev,
    const float* __restrict__ W, const float* __restrict__ Mu,
    const float* __restrict__ Sig, const float* __restrict__ Erev,
    float* __restrict__ out)
{
    const int b = blockIdx.x;
    const int t = threadIdx.x;
    const int i = t & 63;
    const int c = t >> 6;   // 0..7

    __shared__ float v_lds[N_];
    __shared__ float pn_lds[8 * 65];
    __shared__ float pd_lds[8 * 65];
    __shared__ float sn_lds[IN_ * N_];
    __shared__ float sd_lds[IN_ * N_];

    // --- recurrent synapse params (8 j's per thread), folded for exp2 ---
    // sigmoid((v-mu)*sig) = 1/(1+exp2(v*A + Bc)), A=-sig*log2e, Bc=mu*sig*log2e
    float A[8], Bc[8], Wr[8], We[8];
#pragma unroll
    for (int jj = 0; jj < 8; ++jj) {
        int idx = (c * 8 + jj) * N_ + i;
        float sg = Sig[idx], m = Mu[idx], w = W[idx], e = Erev[idx];
        A[jj]  = -sg * LOG2E;
        Bc[jj] = m * sg * LOG2E;
        Wr[jj] = w;
        We[jj] = w * e;
    }

    // --- sensory params: one (in=c, i) element per thread on waves 0..5 ---
    float SA = 0.f, SB = 0.f, SWv = 0.f, SWe = 0.f, nscale = 0.f, nbias = 0.f;
    if (c < IN_) {
        int idx = c * N_ + i;
        float sg = sSig[idx], m = sMu[idx], w = sW[idx], e = sErev[idx];
        SA  = -sg * LOG2E;
        SB  = m * sg * LOG2E;
        SWv = w;
        SWe = w * e;
        nscale = input_w[c] / std_us[c];
        nbias  = input_b[c] - mean_us[c] / std_us[c] * input_w[c];
    }

    // --- wave-0 per-neuron state params ---
    float cmt = 0.f, glk = 0.f, gv = 0.f, v_reg = 0.f, OW = 0.f, OB = 0.f;
    if (c == 0) {
        cmt = cm[i] * (float)UNF;
        glk = gleak[i];
        gv  = glk * vleak[i];
        v_lds[i] = 0.0f;
        if (i < MOT_) {
            OW = output_w[i] * std_us[i];
            OB = output_b[i] * std_us[i] + mean_us[i];
        }
    }
    __syncthreads();

    const float* xb = x + (size_t)b * S_ * IN_;
    float* ob = out + (size_t)b * S_ * MOT_;

    // prefetch input one step ahead (hide global-load latency under the step)
    float xcur = 0.f, xnext = 0.f;
    if (c < IN_) xcur = xb[c];

    float wns = 0.f, wds = 0.f;

    for (int s = 0; s < S_; ++s) {
        if (c < IN_ && s + 1 < S_) xnext = xb[(s + 1) * IN_ + c];

        // sensory synapse activations for this step (waves 0..5, one element each)
        if (c < IN_) {
            float u  = xcur * nscale + nbias;
            float e  = __builtin_amdgcn_exp2f(u * SA + SB);
            float sg = __builtin_amdgcn_rcpf(1.0f + e);
            sn_lds[c * N_ + i] = SWe * sg;
            sd_lds[c * N_ + i] = SWv * sg;
        }

        for (int k = 0; k < UNF; ++k) {
            float pn = 0.f, pd = 0.f;
#pragma unroll
            for (int jj = 0; jj < 8; ++jj) {
                float vj = v_lds[c * 8 + jj];           // broadcast read
                float e  = __builtin_amdgcn_exp2f(vj * A[jj] + Bc[jj]);
                float sg = __builtin_amdgcn_rcpf(1.0f + e);
                pn += We[jj] * sg;
                pd += Wr[jj] * sg;
            }
            pn_lds[c * 65 + i] = pn;
            pd_lds[c * 65 + i] = pd;
            __syncthreads();

            if (c == 0) {
                if (k == 0) {
                    float a = 0.f, d2 = 0.f;
#pragma unroll
                    for (int cc = 0; cc < IN_; ++cc) {
                        a  += sn_lds[cc * N_ + i];
                        d2 += sd_lds[cc * N_ + i];
                    }
                    wns = a; wds = d2;
                }
                float num = cmt * v_reg + gv + wns;
                float den = cmt + glk + wds + EPS_;
#pragma unroll
                for (int cc = 0; cc < 8; ++cc) {
                    num += pn_lds[cc * 65 + i];
                    den += pd_lds[cc * 65 + i];
                }
                v_reg = num * __builtin_amdgcn_rcpf(den);
                v_lds[i] = v_reg;
            }
            __syncthreads();
        }

        // output: motor neurons 0..2, scaled + denormalized (wave 0 lanes 0..2)
        if (t < MOT_) ob[s * MOT_ + t] = v_reg * OW + OB;
        xcur = xnext;
    }
}

extern "C" void kernel_launch(void* const* d_in, const int* in_sizes, int n_in,
                              void* d_out, int out_size, void* d_ws, size_t ws_size,
                              hipStream_t stream) {
    (void)in_sizes; (void)n_in; (void)d_ws; (void)ws_size; (void)out_size;
    const float* x       = (const float*)d_in[0];
    const float* mean_us = (const float*)d_in[1];
    const float* std_us  = (const float*)d_in[2];
    const float* input_w = (const float*)d_in[3];
    const float* input_b = (const float*)d_in[4];
    const float* out_w   = (const float*)d_in[5];
    const float* out_b   = (const float*)d_in[6];
    const float* gleak   = (const float*)d_in[7];
    const float* vleak   = (const float*)d_in[8];
    const float* cm      = (const float*)d_in[9];
    const float* sW      = (const float*)d_in[10];
    const float* sMu     = (const float*)d_in[11];
    const float* sSig    = (const float*)d_in[12];
    const float* sErev   = (const float*)d_in[13];
    const float* W       = (const float*)d_in[14];
    const float* Mu      = (const float*)d_in[15];
    const float* Sig     = (const float*)d_in[16];
    const float* Erev    = (const float*)d_in[17];
    float* out = (float*)d_out;

    ltc_kernel<<<dim3(B_), dim3(512), 0, stream>>>(
        x, mean_us, std_us, input_w, input_b, out_w, out_b,
        gleak, vleak, cm, sW, sMu, sSig, sErev, W, Mu, Sig, Erev, out);
}

// Round 3
// 11220.448 us; speedup vs baseline: 1.1103x; 1.1103x over previous
//
#include <hip/hip_runtime.h>

#define B_ 128
#define S_ 4096
#define IN_ 6
#define N_ 64
#define MOT_ 3
#define UNF 6
#define EPS_ 1e-8f
#define LOG2E 1.4426950408889634f

__device__ __forceinline__ float bperm(int addr, float v) {
    return __int_as_float(__builtin_amdgcn_ds_bpermute(addr, __float_as_int(v)));
}

// One workgroup per batch chain. 512 threads = 8 waves.
// Wave w owns output columns w*8..w*8+7. Lane l = (cc=l>>3 j-chunk, ii=l&7 col).
// Per unfold: each lane computes an 8-synapse partial for its column, then a
// 3-stage in-wave xor-butterfly (over cc) reduces to the full column sum —
// no serial wave, ONE barrier per unfold (v broadcast via double-buffered LDS).
__launch_bounds__(512, 1)
__global__ void ltc_kernel(
    const float* __restrict__ x,
    const float* __restrict__ mean_us, const float* __restrict__ std_us,
    const float* __restrict__ input_w, const float* __restrict__ input_b,
    const float* __restrict__ output_w, const float* __restrict__ output_b,
    const float* __restrict__ gleak, const float* __restrict__ vleak,
    const float* __restrict__ cm,
    const float* __restrict__ sW, const float* __restrict__ sMu,
    const float* __restrict__ sSig, const float* __restrict__ sErev,
    const float* __restrict__ W, const float* __restrict__ Mu,
    const float* __restrict__ Sig, const float* __restrict__ Erev,
    float* __restrict__ out)
{
    const int b    = blockIdx.x;
    const int t    = threadIdx.x;
    const int lane = t & 63;
    const int w    = t >> 6;      // wave 0..7
    const int cc   = lane >> 3;   // j-chunk 0..7
    const int ii   = lane & 7;    // column within wave's block
    const int myCol = w * 8 + ii;
    const int jb   = cc * 8;

    __shared__ __align__(16) float vbuf[2][N_];
    __shared__ float s_lds[IN_][N_][2];   // {wns_term, wds_term} per (input, col)

    // --- recurrent synapse params: 8 synapses (j=jb..jb+7) of column myCol ---
    // sigmoid((v-mu)*sig) = 1/(1+exp2(v*A + Bc)), A=-sig*log2e, Bc=mu*sig*log2e
    float A[8], Bc[8], Wr[8], We[8];
#pragma unroll
    for (int jj = 0; jj < 8; ++jj) {
        int idx = (jb + jj) * N_ + myCol;
        float sg = Sig[idx], m = Mu[idx], ww = W[idx], e = Erev[idx];
        A[jj]  = -sg * LOG2E;
        Bc[jj] = m * sg * LOG2E;
        Wr[jj] = ww;
        We[jj] = ww * e;
    }

    // --- per-column state consts ---
    const float cmt = cm[myCol] * (float)UNF;
    const float glk = gleak[myCol];
    const float gv  = glk * vleak[myCol];

    // --- sensory params: wave w handles input w (w<6), column = lane ---
    float SA = 0.f, SB = 0.f, SWv = 0.f, SWe = 0.f, nscale = 0.f, nbias = 0.f;
    if (w < IN_) {
        int idx = w * N_ + lane;
        float sg = sSig[idx], m = sMu[idx], ww = sW[idx], e = sErev[idx];
        SA  = -sg * LOG2E;
        SB  = m * sg * LOG2E;
        SWv = ww;
        SWe = ww * e;
        nscale = input_w[w] / std_us[w];
        nbias  = input_b[w] - mean_us[w] / std_us[w] * input_w[w];
    }

    // --- output consts (lanes 0..2 of wave 0 hold motor columns 0..2) ---
    float OW = 0.f, OB = 0.f;
    if (t < MOT_) {
        OW = output_w[t] * std_us[t];
        OB = output_b[t] * std_us[t] + mean_us[t];
    }

    const float* xb = x + (size_t)b * S_ * IN_;
    float* ob = out + (size_t)b * S_ * MOT_;

    // --- init: v=0, sensory activations for step 0 ---
    if (t < N_) vbuf[0][t] = 0.f;
    if (w < IN_) {
        float u  = xb[w] * nscale + nbias;
        float e  = __builtin_amdgcn_exp2f(u * SA + SB);
        float sg = __builtin_amdgcn_rcpf(1.0f + e);
        s_lds[w][lane][0] = SWe * sg;
        s_lds[w][lane][1] = SWv * sg;
    }
    __syncthreads();

    const int bp8  = (lane ^ 8)  << 2;
    const int bp16 = (lane ^ 16) << 2;
    const int bp32 = (lane ^ 32) << 2;

    float v_my = 0.f, nb = 0.f, db = 0.f, xnext = 0.f;

    for (int s = 0; s < S_; ++s) {
        // prefetch next step's input (wave-uniform address)
        if (w < IN_) xnext = xb[((s + 1 < S_) ? (s + 1) : s) * IN_ + w];

#pragma unroll
        for (int k = 0; k < UNF; ++k) {
            const int p = k & 1;
            // broadcast-read the 8 v's of this lane's j-chunk (2x ds_read_b128)
            float4 va = *(const float4*)&vbuf[p][jb];
            float4 vc = *(const float4*)&vbuf[p][jb + 4];
            const float vj[8] = {va.x, va.y, va.z, va.w, vc.x, vc.y, vc.z, vc.w};

            float pn = 0.f, pd = 0.f;
#pragma unroll
            for (int jj = 0; jj < 8; ++jj) {
                float e  = __builtin_amdgcn_exp2f(vj[jj] * A[jj] + Bc[jj]);
                float sg = __builtin_amdgcn_rcpf(1.0f + e);
                pn += We[jj] * sg;
                pd += Wr[jj] * sg;
            }
            // in-wave butterfly over cc (lane bits 3,4,5): full column sums
            pn += bperm(bp8,  pn);  pd += bperm(bp8,  pd);
            pn += bperm(bp16, pn);  pd += bperm(bp16, pd);
            pn += bperm(bp32, pn);  pd += bperm(bp32, pd);

            if (k == 0) {
                // fold sensory + leak into per-step bases (6x ds_read_b64 broadcast)
                float a = 0.f, d = 0.f;
#pragma unroll
                for (int ci = 0; ci < IN_; ++ci) {
                    a += s_lds[ci][myCol][0];
                    d += s_lds[ci][myCol][1];
                }
                nb = gv + a;
                db = cmt + glk + d + EPS_;
            }

            float num = cmt * v_my + nb + pn;
            v_my = num * __builtin_amdgcn_rcpf(db + pd);

            // publish v for next unfold (double-buffered, one writer per column)
            if (cc == 0) vbuf[p ^ 1][w * 8 + ii] = v_my;

            if (k == UNF - 1 && w < IN_) {
                // sensory activations for step s+1 (single-buffered is safe:
                // any k==0 reader of s_lds is >=5 barriers behind this write)
                float u  = xnext * nscale + nbias;
                float e2 = __builtin_amdgcn_exp2f(u * SA + SB);
                float sg = __builtin_amdgcn_rcpf(1.0f + e2);
                s_lds[w][lane][0] = SWe * sg;
                s_lds[w][lane][1] = SWv * sg;
            }
            __syncthreads();
        }

        // motor outputs: columns 0..2 live in lanes 0..2 of wave 0
        if (t < MOT_) ob[s * MOT_ + t] = v_my * OW + OB;
    }
}

extern "C" void kernel_launch(void* const* d_in, const int* in_sizes, int n_in,
                              void* d_out, int out_size, void* d_ws, size_t ws_size,
                              hipStream_t stream) {
    (void)in_sizes; (void)n_in; (void)d_ws; (void)ws_size; (void)out_size;
    const float* x       = (const float*)d_in[0];
    const float* mean_us = (const float*)d_in[1];
    const float* std_us  = (const float*)d_in[2];
    const float* input_w = (const float*)d_in[3];
    const float* input_b = (const float*)d_in[4];
    const float* out_w   = (const float*)d_in[5];
    const float* out_b   = (const float*)d_in[6];
    const float* gleak   = (const float*)d_in[7];
    const float* vleak   = (const float*)d_in[8];
    const float* cm      = (const float*)d_in[9];
    const float* sW      = (const float*)d_in[10];
    const float* sMu     = (const float*)d_in[11];
    const float* sSig    = (const float*)d_in[12];
    const float* sErev   = (const float*)d_in[13];
    const float* W       = (const float*)d_in[14];
    const float* Mu      = (const float*)d_in[15];
    const float* Sig     = (const float*)d_in[16];
    const float* Erev    = (const float*)d_in[17];
    float* out = (float*)d_out;

    ltc_kernel<<<dim3(B_), dim3(512), 0, stream>>>(
        x, mean_us, std_us, input_w, input_b, out_w, out_b,
        gleak, vleak, cm, sW, sMu, sSig, sErev, W, Mu, Sig, Erev, out);
}

// Round 4
// 10406.400 us; speedup vs baseline: 1.1971x; 1.0782x over previous
//
#include <hip/hip_runtime.h>

#define B_ 128
#define S_ 4096
#define IN_ 6
#define N_ 64
#define MOT_ 3
#define UNF 6
#define EPS_ 1e-8f
#define LOG2E 1.4426950408889634f

// ---- VALU-pipe cross-lane reductions over lane bits 3,4,5 (cc) ----
__device__ __forceinline__ float red8(float x) {
    // partner = lane^8 : rotation by 8 within each 16-lane row == xor8
    int r = __builtin_amdgcn_update_dpp(0, __float_as_int(x), 0x128 /*row_ror:8*/,
                                        0xF, 0xF, true);
    return x + __int_as_float(r);
}
__device__ __forceinline__ float red16(float x) {
#if __has_builtin(__builtin_amdgcn_permlane16_swap)
    auto r = __builtin_amdgcn_permlane16_swap(__float_as_int(x), __float_as_int(x),
                                              false, false);
    return __int_as_float((int)r[0]) + __int_as_float((int)r[1]);
#else
    return x + __shfl_xor(x, 16, 64);
#endif
}
__device__ __forceinline__ float red32(float x) {
#if __has_builtin(__builtin_amdgcn_permlane32_swap)
    auto r = __builtin_amdgcn_permlane32_swap(__float_as_int(x), __float_as_int(x),
                                              false, false);
    return __int_as_float((int)r[0]) + __int_as_float((int)r[1]);
#else
    return x + __shfl_xor(x, 32, 64);
#endif
}

// barrier with LDS-only drain (no vmcnt: global loads/stores stay in flight)
__device__ __forceinline__ void lds_barrier() {
    asm volatile("s_waitcnt lgkmcnt(0)" ::: "memory");
    __builtin_amdgcn_s_barrier();
}

// One workgroup per batch chain. 512 threads = 8 waves.
// Wave w owns output columns w*8..w*8+7. Lane l = (cc=l>>3 j-chunk, ii=l&7 col).
// Per unfold: 8-synapse partial per lane, then a 3-stage VALU butterfly
// (DPP row_ror:8 + permlane16/32_swap) -> full column sums in-register.
// ONE lgkm-only barrier per unfold (v exchanged via double-buffered LDS).
__launch_bounds__(512, 1)
__global__ void ltc_kernel(
    const float* __restrict__ x,
    const float* __restrict__ mean_us, const float* __restrict__ std_us,
    const float* __restrict__ input_w, const float* __restrict__ input_b,
    const float* __restrict__ output_w, const float* __restrict__ output_b,
    const float* __restrict__ gleak, const float* __restrict__ vleak,
    const float* __restrict__ cm,
    const float* __restrict__ sW, const float* __restrict__ sMu,
    const float* __restrict__ sSig, const float* __restrict__ sErev,
    const float* __restrict__ W, const float* __restrict__ Mu,
    const float* __restrict__ Sig, const float* __restrict__ Erev,
    float* __restrict__ out)
{
    const int b    = blockIdx.x;
    const int t    = threadIdx.x;
    const int lane = t & 63;
    const int w    = t >> 6;      // wave 0..7
    const int cc   = lane >> 3;   // j-chunk 0..7
    const int ii   = lane & 7;    // column within wave's block
    const int myCol = w * 8 + ii;
    const int jb   = cc * 8;

    __shared__ __align__(16) float vbuf[2][N_];
    __shared__ float s_lds[IN_][N_][2];   // {wns_term, wds_term} per (input, col)

    // --- recurrent synapse params: 8 synapses (j=jb..jb+7) of column myCol ---
    // sigmoid((v-mu)*sig) = 1/(1+exp2(v*A + Bc)), A=-sig*log2e, Bc=mu*sig*log2e
    float A[8], Bc[8], Wr[8], We[8];
#pragma unroll
    for (int jj = 0; jj < 8; ++jj) {
        int idx = (jb + jj) * N_ + myCol;
        float sg = Sig[idx], m = Mu[idx], ww = W[idx], e = Erev[idx];
        A[jj]  = -sg * LOG2E;
        Bc[jj] = m * sg * LOG2E;
        Wr[jj] = ww;
        We[jj] = ww * e;
    }

    // --- per-column state consts ---
    const float cmt = cm[myCol] * (float)UNF;
    const float glk = gleak[myCol];
    const float gv  = glk * vleak[myCol];
    const float dbase = cmt + glk + EPS_;

    // --- sensory params: wave w handles input w (w<6), column = lane ---
    float SA = 0.f, SB = 0.f, SWv = 0.f, SWe = 0.f, nscale = 0.f, nbias = 0.f;
    if (w < IN_) {
        int idx = w * N_ + lane;
        float sg = sSig[idx], m = sMu[idx], ww = sW[idx], e = sErev[idx];
        SA  = -sg * LOG2E;
        SB  = m * sg * LOG2E;
        SWv = ww;
        SWe = ww * e;
        nscale = input_w[w] / std_us[w];
        nbias  = input_b[w] - mean_us[w] / std_us[w] * input_w[w];
    }

    // --- output consts (lanes 0..2 of wave 0 hold motor columns 0..2) ---
    float OW = 0.f, OB = 0.f;
    if (t < MOT_) {
        OW = output_w[t] * std_us[t];
        OB = output_b[t] * std_us[t] + mean_us[t];
    }

    const float* xb = x + (size_t)b * S_ * IN_;
    float* ob = out + (size_t)b * S_ * MOT_;

    // --- init: v=0, sensory activations for step 0 ---
    if (t < N_) vbuf[0][t] = 0.f;
    if (w < IN_) {
        float u  = fmaf(xb[w], nscale, nbias);
        float e  = __builtin_amdgcn_exp2f(fmaf(u, SA, SB));
        float sg = __builtin_amdgcn_rcpf(1.0f + e);
        s_lds[w][lane][0] = SWe * sg;
        s_lds[w][lane][1] = SWv * sg;
    }
    lds_barrier();

    float v_my = 0.f;

    for (int s = 0; s < S_; ++s) {
        // prefetch next step's input (wave-uniform addr; consumed at k==1)
        float xnext = 0.f;
        if (w < IN_) xnext = xb[((s + 1 < S_) ? (s + 1) : s) * IN_ + w];

        // fold sensory + leak into per-step bases (6x broadcast ds_read_b64;
        // consumed only after unfold-0's butterfly -> latency overlapped)
        float a = 0.f, d = 0.f;
#pragma unroll
        for (int ci = 0; ci < IN_; ++ci) {
            float2 sv = *(const float2*)&s_lds[ci][myCol][0];
            a += sv.x; d += sv.y;
        }
        const float nb = gv + a;
        const float db = dbase + d;

#pragma unroll
        for (int k = 0; k < UNF; ++k) {
            const int p = k & 1;
            // broadcast-read the 8 v's of this lane's j-chunk (2x ds_read_b128)
            float4 va = *(const float4*)&vbuf[p][jb];
            float4 vc = *(const float4*)&vbuf[p][jb + 4];
            const float vj[8] = {va.x, va.y, va.z, va.w, vc.x, vc.y, vc.z, vc.w};

            float pn = 0.f, pd = 0.f;
#pragma unroll
            for (int jj = 0; jj < 8; ++jj) {
                float e  = __builtin_amdgcn_exp2f(fmaf(vj[jj], A[jj], Bc[jj]));
                float sg = __builtin_amdgcn_rcpf(1.0f + e);
                pn = fmaf(We[jj], sg, pn);
                pd = fmaf(Wr[jj], sg, pd);
            }
            // VALU butterfly over cc (lane bits 3,4,5): full column sums
            pn = red8(pn);   pd = red8(pd);
            pn = red16(pn);  pd = red16(pd);
            pn = red32(pn);  pd = red32(pd);

            float num = fmaf(cmt, v_my, nb + pn);
            v_my = num * __builtin_amdgcn_rcpf(db + pd);

            // publish v for next unfold (double-buffered, one writer per column)
            if (cc == 0) vbuf[p ^ 1][myCol] = v_my;

            if (k == 1 && w < IN_) {
                // sensory activations for step s+1 (write is 1+ barriers after
                // all step-s readers, and 4 barriers before step-s+1 readers)
                float u  = fmaf(xnext, nscale, nbias);
                float e2 = __builtin_amdgcn_exp2f(fmaf(u, SA, SB));
                float sg = __builtin_amdgcn_rcpf(1.0f + e2);
                s_lds[w][lane][0] = SWe * sg;
                s_lds[w][lane][1] = SWv * sg;
            }
            lds_barrier();
        }

        // motor outputs: columns 0..2 live in lanes 0..2 of wave 0
        if (t < MOT_) ob[s * MOT_ + t] = fmaf(v_my, OW, OB);
    }
}

extern "C" void kernel_launch(void* const* d_in, const int* in_sizes, int n_in,
                              void* d_out, int out_size, void* d_ws, size_t ws_size,
                              hipStream_t stream) {
    (void)in_sizes; (void)n_in; (void)d_ws; (void)ws_size; (void)out_size;
    const float* x       = (const float*)d_in[0];
    const float* mean_us = (const float*)d_in[1];
    const float* std_us  = (const float*)d_in[2];
    const float* input_w = (const float*)d_in[3];
    const float* input_b = (const float*)d_in[4];
    const float* out_w   = (const float*)d_in[5];
    const float* out_b   = (const float*)d_in[6];
    const float* gleak   = (const float*)d_in[7];
    const float* vleak   = (const float*)d_in[8];
    const float* cm      = (const float*)d_in[9];
    const float* sW      = (const float*)d_in[10];
    const float* sMu     = (const float*)d_in[11];
    const float* sSig    = (const float*)d_in[12];
    const float* sErev   = (const float*)d_in[13];
    const float* W       = (const float*)d_in[14];
    const float* Mu      = (const float*)d_in[15];
    const float* Sig     = (const float*)d_in[16];
    const float* Erev    = (const float*)d_in[17];
    float* out = (float*)d_out;

    ltc_kernel<<<dim3(B_), dim3(512), 0, stream>>>(
        x, mean_us, std_us, input_w, input_b, out_w, out_b,
        gleak, vleak, cm, sW, sMu, sSig, sErev, W, Mu, Sig, Erev, out);
}

// Round 5
// 9592.833 us; speedup vs baseline: 1.2986x; 1.0848x over previous
//
#include <hip/hip_runtime.h>

#define B_ 128
#define S_ 4096
#define IN_ 6
#define N_ 64
#define MOT_ 3
#define UNF 6
#define EPS_ 1e-8f
#define LOG2E 1.4426950408889634f

// ---- VALU-pipe cross-lane pair-sums over lane bits 4 and 5 ----
__device__ __forceinline__ float red16(float x) {
#if __has_builtin(__builtin_amdgcn_permlane16_swap)
    auto r = __builtin_amdgcn_permlane16_swap(__float_as_int(x), __float_as_int(x),
                                              false, false);
    return __int_as_float((int)r[0]) + __int_as_float((int)r[1]);
#else
    return x + __shfl_xor(x, 16, 64);
#endif
}
__device__ __forceinline__ float red32(float x) {
#if __has_builtin(__builtin_amdgcn_permlane32_swap)
    auto r = __builtin_amdgcn_permlane32_swap(__float_as_int(x), __float_as_int(x),
                                              false, false);
    return __int_as_float((int)r[0]) + __int_as_float((int)r[1]);
#else
    return x + __shfl_xor(x, 32, 64);
#endif
}

// barrier with LDS-only drain (no vmcnt: global loads/stores stay in flight)
__device__ __forceinline__ void lds_barrier() {
    asm volatile("s_waitcnt lgkmcnt(0)" ::: "memory");
    __builtin_amdgcn_s_barrier();
}

// One workgroup per batch chain. 256 threads = 4 waves = 1 wave/SIMD
// (no trans-pipe contention). Wave w owns output columns w*16..w*16+15.
// Lane l = (cc=l>>4 j-chunk of 16, ii=l&15 col). Per unfold: 16-synapse
// partial per lane, 2-stage VALU butterfly (permlane16/32_swap) -> full
// column sums in-register. ONE lgkm-only barrier per unfold.
__launch_bounds__(256, 1)
__global__ void ltc_kernel(
    const float* __restrict__ x,
    const float* __restrict__ mean_us, const float* __restrict__ std_us,
    const float* __restrict__ input_w, const float* __restrict__ input_b,
    const float* __restrict__ output_w, const float* __restrict__ output_b,
    const float* __restrict__ gleak, const float* __restrict__ vleak,
    const float* __restrict__ cm,
    const float* __restrict__ sW, const float* __restrict__ sMu,
    const float* __restrict__ sSig, const float* __restrict__ sErev,
    const float* __restrict__ W, const float* __restrict__ Mu,
    const float* __restrict__ Sig, const float* __restrict__ Erev,
    float* __restrict__ out)
{
    const int b    = blockIdx.x;
    const int t    = threadIdx.x;
    const int lane = t & 63;
    const int w    = t >> 6;      // wave 0..3
    const int cc   = lane >> 4;   // j-chunk 0..3 (16 j's each)
    const int ii   = lane & 15;   // column within wave's block
    const int myCol = w * 16 + ii;
    const int jb   = cc * 16;

    __shared__ __align__(16) float vbuf[2][N_];
    __shared__ float s_lds[IN_][N_][2];   // {wns_term, wds_term} per (input, col)

    // --- recurrent synapse params: 16 synapses (j=jb..jb+15) of column myCol ---
    // sigmoid((v-mu)*sig) = 1/(1+exp2(v*A + Bc)), A=-sig*log2e, Bc=mu*sig*log2e
    float A[16], Bc[16], Wr[16], We[16];
#pragma unroll
    for (int jj = 0; jj < 16; ++jj) {
        int idx = (jb + jj) * N_ + myCol;
        float sg = Sig[idx], m = Mu[idx], ww = W[idx], e = Erev[idx];
        A[jj]  = -sg * LOG2E;
        Bc[jj] = m * sg * LOG2E;
        Wr[jj] = ww;
        We[jj] = ww * e;
    }

    // --- per-column state consts ---
    const float cmt = cm[myCol] * (float)UNF;
    const float glk = gleak[myCol];
    const float gv  = glk * vleak[myCol];
    const float dbase = cmt + glk + EPS_;

    // --- sensory params: wave w handles input w; waves 0,1 also input w+4 ---
    const int i0 = w;             // always valid (w<4 < IN_=6)
    const int i1 = w + 4;         // valid for w<2
    const bool has1 = (w < 2);
    float SA0, SB0, SWv0, SWe0, ns0, nb0;
    {
        int idx = i0 * N_ + lane;
        float sg = sSig[idx], m = sMu[idx], ww = sW[idx], e = sErev[idx];
        SA0 = -sg * LOG2E; SB0 = m * sg * LOG2E; SWv0 = ww; SWe0 = ww * e;
        ns0 = input_w[i0] / std_us[i0];
        nb0 = input_b[i0] - mean_us[i0] / std_us[i0] * input_w[i0];
    }
    float SA1 = 0.f, SB1 = 0.f, SWv1 = 0.f, SWe1 = 0.f, ns1 = 0.f, nb1 = 0.f;
    if (has1) {
        int idx = i1 * N_ + lane;
        float sg = sSig[idx], m = sMu[idx], ww = sW[idx], e = sErev[idx];
        SA1 = -sg * LOG2E; SB1 = m * sg * LOG2E; SWv1 = ww; SWe1 = ww * e;
        ns1 = input_w[i1] / std_us[i1];
        nb1 = input_b[i1] - mean_us[i1] / std_us[i1] * input_w[i1];
    }

    // --- output consts (lanes 0..2 of wave 0 hold motor columns 0..2) ---
    float OW = 0.f, OB = 0.f;
    if (t < MOT_) {
        OW = output_w[t] * std_us[t];
        OB = output_b[t] * std_us[t] + mean_us[t];
    }

    const float* xb = x + (size_t)b * S_ * IN_;
    float* ob = out + (size_t)b * S_ * MOT_;

    // --- init: v=0, sensory activations for step 0 ---
    if (t < N_) vbuf[0][t] = 0.f;
    {
        float u  = fmaf(xb[i0], ns0, nb0);
        float e  = __builtin_amdgcn_exp2f(fmaf(u, SA0, SB0));
        float sg = __builtin_amdgcn_rcpf(1.0f + e);
        s_lds[i0][lane][0] = SWe0 * sg;
        s_lds[i0][lane][1] = SWv0 * sg;
        if (has1) {
            float u1  = fmaf(xb[i1], ns1, nb1);
            float e1  = __builtin_amdgcn_exp2f(fmaf(u1, SA1, SB1));
            float sg1 = __builtin_amdgcn_rcpf(1.0f + e1);
            s_lds[i1][lane][0] = SWe1 * sg1;
            s_lds[i1][lane][1] = SWv1 * sg1;
        }
    }
    lds_barrier();

    float v_my = 0.f;

    for (int s = 0; s < S_; ++s) {
        // prefetch next step's input (wave-uniform addr; consumed at k==1)
        const int s1 = (s + 1 < S_) ? (s + 1) : s;
        float xn0 = xb[s1 * IN_ + i0];
        float xn1 = has1 ? xb[s1 * IN_ + i1] : 0.f;

        // fold sensory + leak into per-step bases (6x broadcast ds_read_b64;
        // consumed only after unfold-0's butterfly -> latency overlapped)
        float a = 0.f, d = 0.f;
#pragma unroll
        for (int ci = 0; ci < IN_; ++ci) {
            float2 sv = *(const float2*)&s_lds[ci][myCol][0];
            a += sv.x; d += sv.y;
        }
        const float nb = gv + a;
        const float db = dbase + d;

#pragma unroll
        for (int k = 0; k < UNF; ++k) {
            const int p = k & 1;
            // broadcast-read the 16 v's of this lane's j-chunk (4x ds_read_b128)
            float4 v0 = *(const float4*)&vbuf[p][jb];
            float4 v1 = *(const float4*)&vbuf[p][jb + 4];
            float4 v2 = *(const float4*)&vbuf[p][jb + 8];
            float4 v3 = *(const float4*)&vbuf[p][jb + 12];
            const float vj[16] = {v0.x, v0.y, v0.z, v0.w, v1.x, v1.y, v1.z, v1.w,
                                  v2.x, v2.y, v2.z, v2.w, v3.x, v3.y, v3.z, v3.w};

            float pn = 0.f, pd = 0.f;
#pragma unroll
            for (int jj = 0; jj < 16; ++jj) {
                float e  = __builtin_amdgcn_exp2f(fmaf(vj[jj], A[jj], Bc[jj]));
                float sg = __builtin_amdgcn_rcpf(1.0f + e);
                pn = fmaf(We[jj], sg, pn);
                pd = fmaf(Wr[jj], sg, pd);
            }
            // VALU butterfly over cc (lane bits 4,5): full column sums
            pn = red16(pn);  pd = red16(pd);
            pn = red32(pn);  pd = red32(pd);

            float num = fmaf(cmt, v_my, nb + pn);
            v_my = num * __builtin_amdgcn_rcpf(db + pd);

            // publish v for next unfold (double-buffered, one writer per column)
            if (cc == 0) vbuf[p ^ 1][myCol] = v_my;

            if (k == 1) {
                // sensory activations for step s+1 (step-s readers are before
                // the k=0 barrier; step-s+1 readers are 4 barriers later)
                float u  = fmaf(xn0, ns0, nb0);
                float e2 = __builtin_amdgcn_exp2f(fmaf(u, SA0, SB0));
                float sg = __builtin_amdgcn_rcpf(1.0f + e2);
                s_lds[i0][lane][0] = SWe0 * sg;
                s_lds[i0][lane][1] = SWv0 * sg;
                if (has1) {
                    float u1  = fmaf(xn1, ns1, nb1);
                    float e3  = __builtin_amdgcn_exp2f(fmaf(u1, SA1, SB1));
                    float sg1 = __builtin_amdgcn_rcpf(1.0f + e3);
                    s_lds[i1][lane][0] = SWe1 * sg1;
                    s_lds[i1][lane][1] = SWv1 * sg1;
                }
            }
            lds_barrier();
        }

        // motor outputs: columns 0..2 live in lanes 0..2 of wave 0
        if (t < MOT_) ob[s * MOT_ + t] = fmaf(v_my, OW, OB);
    }
}

extern "C" void kernel_launch(void* const* d_in, const int* in_sizes, int n_in,
                              void* d_out, int out_size, void* d_ws, size_t ws_size,
                              hipStream_t stream) {
    (void)in_sizes; (void)n_in; (void)d_ws; (void)ws_size; (void)out_size;
    const float* x       = (const float*)d_in[0];
    const float* mean_us = (const float*)d_in[1];
    const float* std_us  = (const float*)d_in[2];
    const float* input_w = (const float*)d_in[3];
    const float* input_b = (const float*)d_in[4];
    const float* out_w   = (const float*)d_in[5];
    const float* out_b   = (const float*)d_in[6];
    const float* gleak   = (const float*)d_in[7];
    const float* vleak   = (const float*)d_in[8];
    const float* cm      = (const float*)d_in[9];
    const float* sW      = (const float*)d_in[10];
    const float* sMu     = (const float*)d_in[11];
    const float* sSig    = (const float*)d_in[12];
    const float* sErev   = (const float*)d_in[13];
    const float* W       = (const float*)d_in[14];
    const float* Mu      = (const float*)d_in[15];
    const float* Sig     = (const float*)d_in[16];
    const float* Erev    = (const float*)d_in[17];
    float* out = (float*)d_out;

    ltc_kernel<<<dim3(B_), dim3(256), 0, stream>>>(
        x, mean_us, std_us, input_w, input_b, out_w, out_b,
        gleak, vleak, cm, sW, sMu, sSig, sErev, W, Mu, Sig, Erev, out);
}